// Round 11
// baseline (336.109 us; speedup 1.0000x reference)
//
#include <hip/hip_runtime.h>

#define BATCH 4
#define CH    256
#define NTOK  4096
#define DQK   32

typedef __attribute__((ext_vector_type(4))) float  f32x4;
typedef __attribute__((ext_vector_type(2))) float  f32x2;
typedef __attribute__((ext_vector_type(8))) __bf16 bf16x8;
typedef __attribute__((ext_vector_type(2))) unsigned int u32x2;
typedef __attribute__((ext_vector_type(4))) unsigned int u32x4;

// round-to-nearest-even float -> bf16 bits (cold paths)
static __device__ __forceinline__ unsigned short f2bf(float f) {
    unsigned int u = __builtin_bit_cast(unsigned int, f);
    unsigned int r = u + 0x7FFFu + ((u >> 16) & 1u);
    return (unsigned short)(r >> 16);
}
static __device__ __forceinline__ unsigned int pack2(float a, float b) {
    return (unsigned int)f2bf(a) | ((unsigned int)f2bf(b) << 16);
}
// hot-path pack: single HW instr, RTNE, a->lo b->hi
static __device__ __forceinline__ unsigned int cvt_pk_bf16(float a, float b) {
    unsigned int r;
    asm("v_cvt_pk_bf16_f32 %0, %1, %2" : "=v"(r) : "v"(a), "v"(b));
    return r;
}

// ---------------------------------------------------------------------------
// Kernel 0: convert Wq|Wk|Wv -> Wbf [320 rows][256 c] bf16; zero Mk.
// (R10's inline-fp32-W fusion REVERTED: it cost +9us e2e — 512 blocks
// re-reading W as fp32 + re-converting beats the single launch it saved.)
// ---------------------------------------------------------------------------
__global__ __launch_bounds__(256)
void wconv(const float* __restrict__ Wq, const float* __restrict__ Wk,
           const float* __restrict__ Wv, unsigned short* __restrict__ Wbf,
           unsigned int* __restrict__ Mk)
{
    if (blockIdx.x == 0 && threadIdx.x < BATCH) Mk[threadIdx.x] = 0u;
    const int id = (blockIdx.x * 256 + threadIdx.x) * 4;
    const int r  = id >> 8;
    const int c  = id & 255;
    const float* src = (r < 32) ? (Wq + r * 256 + c)
                     : (r < 64) ? (Wk + (r - 32) * 256 + c)
                                : (Wv + (size_t)(r - 64) * 256 + c);
    float v0 = src[0], v1 = src[1], v2 = src[2], v3 = src[3];
    u32x2 p = {pack2(v0, v1), pack2(v2, v3)};
    *reinterpret_cast<u32x2*>(Wbf + id) = p;
}

// ---------------------------------------------------------------------------
// Kernel 1: QKV projection, LDS-staged coalesced x reads (R8-verified exact).
// ---------------------------------------------------------------------------
__global__ __launch_bounds__(256, 2)
void qkv_proj(const float* __restrict__ x,
              const float* __restrict__ pbq, const float* __restrict__ pbk,
              const float* __restrict__ pbv,
              const unsigned short* __restrict__ Wbf,
              unsigned short* __restrict__ Qh,
              unsigned short* __restrict__ Kh,
              unsigned short* __restrict__ Vh,
              unsigned int* __restrict__ Mk)
{
    const int t    = threadIdx.x;
    const int wave = t >> 6;
    const int lane = t & 63;
    const int low  = lane & 15;
    const int quad = lane >> 4;
    const int blk  = blockIdx.x;
    const int b    = blk >> 7;               // 128 blocks per batch
    const int tok0 = (blk & 127) * 32;

    __shared__ unsigned short xs[256 * 38];  // x^T tile bf16 [c][38]; V re-aliases

    // ---- stage x[b][:, tok0:tok0+32] -> xs (coalesced 128B segments) ----
    {
        const float* xg = x + (size_t)b * CH * NTOK + tok0;
        const int k  = t & 7;                // 4-token group
        const int c0 = t >> 3;               // 0..31
        #pragma unroll
        for (int p = 0; p < 8; ++p) {
            const int c = p * 32 + c0;
            const f32x4 v = *reinterpret_cast<const f32x4*>(
                xg + (size_t)c * NTOK + k * 4);
            unsigned int* dst = reinterpret_cast<unsigned int*>(xs + c * 38 + k * 4);
            dst[0] = cvt_pk_bf16(v[0], v[1]);
            dst[1] = cvt_pk_bf16(v[2], v[3]);
        }
    }

    // bias init: acc[j][tt], rows rtg = wave*5+j, token-tiles tt=0,1
    f32x4 acc[5][2];
    #pragma unroll
    for (int j = 0; j < 5; ++j) {
        const int rtg = wave * 5 + j;
        float bb = (rtg < 2) ? pbq[rtg * 16 + low]
                 : (rtg < 4) ? pbk[(rtg - 2) * 16 + low]
                             : pbv[(rtg - 4) * 16 + low];
        f32x4 z = {bb, bb, bb, bb};
        acc[j][0] = z; acc[j][1] = z;
    }

    __syncthreads();

    #pragma unroll
    for (int k0 = 0; k0 < 8; ++k0) {
        bf16x8 wf[5];
        #pragma unroll
        for (int j = 0; j < 5; ++j) {
            const int rtg = wave * 5 + j;
            wf[j] = *reinterpret_cast<const bf16x8*>(
                Wbf + (size_t)(rtg * 16 + low) * 256 + k0 * 32 + quad * 8);
        }
        #pragma unroll
        for (int tt = 0; tt < 2; ++tt) {
            // A fragment: token = tt*16+low, channels k0*32+quad*8+e
            const unsigned short* xsrc = xs + (k0 * 32 + quad * 8) * 38 + tt * 16 + low;
            unsigned int w0 = (unsigned int)xsrc[0 * 38] | ((unsigned int)xsrc[1 * 38] << 16);
            unsigned int w1 = (unsigned int)xsrc[2 * 38] | ((unsigned int)xsrc[3 * 38] << 16);
            unsigned int w2 = (unsigned int)xsrc[4 * 38] | ((unsigned int)xsrc[5 * 38] << 16);
            unsigned int w3 = (unsigned int)xsrc[6 * 38] | ((unsigned int)xsrc[7 * 38] << 16);
            u32x4 ap = {w0, w1, w2, w3};
            const bf16x8 af = __builtin_bit_cast(bf16x8, ap);
            #pragma unroll
            for (int j = 0; j < 5; ++j)
                acc[j][tt] = __builtin_amdgcn_mfma_f32_16x16x32_bf16(
                    af, wf[j], acc[j][tt], 0, 0, 0);
        }
    }

    // ---- Q/K epilogue ----
    #pragma unroll
    for (int j = 0; j < 5; ++j) {
        const int rtg = wave * 5 + j;
        if (rtg < 4) {
            unsigned short* dst = (rtg < 2) ? Qh : Kh;
            const int wr = (rtg & 1) * 16 + low;
            #pragma unroll
            for (int tt = 0; tt < 2; ++tt)
                #pragma unroll
                for (int reg = 0; reg < 4; ++reg) {
                    const int token = tok0 + tt * 16 + quad * 4 + reg;
                    dst[(size_t)(b * NTOK + token) * DQK + wr] = f2bf(acc[j][tt][reg]);
                }
        }
    }
    // ---- per-batch max||k||^2 (wave 0: acc[2],acc[3] = K dims 0..31) ----
    if (wave == 0) {
        #pragma unroll
        for (int tt = 0; tt < 2; ++tt) {
            f32x4 kk = acc[2][tt] * acc[2][tt] + acc[3][tt] * acc[3][tt];
            #pragma unroll
            for (int mask = 1; mask <= 8; mask <<= 1)
                #pragma unroll
                for (int reg = 0; reg < 4; ++reg)
                    kk[reg] += __shfl_xor(kk[reg], mask);
            if (low == 0) {
                #pragma unroll
                for (int reg = 0; reg < 4; ++reg)
                    atomicMax(&Mk[b], __builtin_bit_cast(unsigned int, kk[reg]));
            }
        }
    }

    // ---- V epilogue: transpose in re-aliased xs (stride 36 u16) ----
    __syncthreads();                         // all xs fragment reads done
    #pragma unroll
    for (int j = 0; j < 5; ++j) {
        const int rtg = wave * 5 + j;
        if (rtg >= 4) {
            const int c = (rtg - 4) * 16 + low;
            #pragma unroll
            for (int tt = 0; tt < 2; ++tt)
                #pragma unroll
                for (int reg = 0; reg < 4; ++reg)
                    xs[c * 36 + tt * 16 + quad * 4 + reg] = f2bf(acc[j][tt][reg]);
        }
    }
    __syncthreads();
    {
        const int k  = t & 7;
        const int c0 = t >> 3;
        #pragma unroll
        for (int p = 0; p < 8; ++p) {
            const int c = p * 32 + c0;
            const u32x2 v = *reinterpret_cast<const u32x2*>(xs + c * 36 + k * 4);
            *reinterpret_cast<u32x2*>(
                Vh + ((size_t)b * CH + c) * NTOK + tok0 + k * 4) = v;
        }
    }
}

// ---------------------------------------------------------------------------
// Kernel 2: flash attention — R11 OCCUPANCY split of the R8-verified kernel.
// Same 64q block, same total work, same 16 iterations, same S(i+1)-before-
// PV(i) wave-private double-buffered P (byte-compatible layout, same 148KB
// LDS) — but 16 waves (kg4 x ch2 x qw2, 1024 thr) instead of 8: per-wave
// state halves (acc[2][8]=64 AGPR, qfrag[2]) so __launch_bounds__(1024,4)
// targets <=128 regs/wave -> 4 waves/SIMD (R8: 2). R9's failure was doubling
// ITERATIONS at constant occupancy; this doubles OCCUPANCY at constant
// iterations. Cost: V/K L2 traffic x2 (q-waves re-read the kg's V stream).
// ---------------------------------------------------------------------------
__global__ __launch_bounds__(1024, 4)
void attn(const float* __restrict__ x,
          const unsigned short* __restrict__ Qh,
          const unsigned short* __restrict__ Kh,
          const unsigned short* __restrict__ Vh,
          const unsigned int* __restrict__ Mk,
          float* __restrict__ out)
{
    const int t    = threadIdx.x;
    const int wave = t >> 6;                 // 0..15
    const int kg   = wave & 3;               // keygroup (4)
    const int ch   = (wave >> 2) & 1;        // channel half
    const int qw   = wave >> 3;              // q-pair (0..1)
    const int lane = t & 63;
    const int low  = lane & 15;
    const int quad = lane >> 4;

    const int beta = blockIdx.x;             // XCD swizzle (perf heuristic)
    const int b    = (beta & 7) >> 1;
    const int q0   = (((beta >> 3) * 2) + (beta & 1)) * 64;

    // dwords: [0,36864) private P, dbuf: buf*18432 + wave*1152 + row*36
    // (row = j*16+low, j=0..1); [36864,37120) lbuf. Merge slabs (16 x 704 dw)
    // alias the P region after the post-loop barrier.
    __shared__ float smem[36864 + 256];
    unsigned int* Pbase = (unsigned int*)smem;
    float* lbuf = smem + 36864;

    const float LOG2E = 1.44269504088896f;

    bf16x8 qfrag[2];
    float  m2[2];
    {
        const float M2 = __builtin_bit_cast(float, Mk[b]);
        #pragma unroll
        for (int j = 0; j < 2; ++j) {
            const int qq = qw * 2 + j;       // global q-subtile 0..3
            qfrag[j] = *reinterpret_cast<const bf16x8*>(
                Qh + (size_t)(b * NTOK + q0 + qq * 16 + low) * DQK + quad * 8);
            float qn2 = 0.f;
            #pragma unroll
            for (int e = 0; e < 8; ++e) {
                float qv = (float)qfrag[j][e];
                qn2 += qv * qv;
            }
            qn2 += __shfl_xor(qn2, 16);
            qn2 += __shfl_xor(qn2, 32);
            m2[j] = __builtin_sqrtf(qn2 * M2) * (1.02f * LOG2E);
        }
    }

    f32x4 acc[2][8];
    #pragma unroll
    for (int j = 0; j < 2; ++j)
        #pragma unroll
        for (int ct = 0; ct < 8; ++ct) { f32x4 z = {0.f,0.f,0.f,0.f}; acc[j][ct] = z; }
    float l_s[2] = {0.f, 0.f};

    const unsigned short* Kb = Kh + (size_t)b * NTOK * DQK;
    const unsigned short* Vb = Vh + (size_t)b * CH * NTOK;

    // S for this wave's 2 q-subtiles, own keygroup, into OWN P region.
    #define S_PHASE(ii, buf)                                                    \
    {                                                                           \
        const int n0s = ((ii) * 4 + kg) * 64;                                   \
        bf16x8 kf[4];                                                           \
        _Pragma("unroll")                                                       \
        for (int kt = 0; kt < 4; ++kt)                                          \
            kf[kt] = *reinterpret_cast<const bf16x8*>(                          \
                Kb + (size_t)(n0s + kt * 16 + low) * DQK + quad * 8);           \
        _Pragma("unroll")                                                       \
        for (int j = 0; j < 2; ++j) {                                           \
            f32x4 S[4];                                                         \
            _Pragma("unroll")                                                   \
            for (int kt = 0; kt < 4; ++kt) {                                    \
                f32x4 z = {0.f,0.f,0.f,0.f};                                    \
                S[kt] = __builtin_amdgcn_mfma_f32_16x16x32_bf16(kf[kt],         \
                            qfrag[j], z, 0, 0, 0);                              \
            }                                                                   \
            float sum = 0.f;                                                    \
            unsigned int* pq = Pbase + (buf) * 18432 + wave * 1152              \
                               + (j * 16 + low) * 36 + quad * 2;                \
            _Pragma("unroll")                                                   \
            for (int kt = 0; kt < 4; ++kt) {                                    \
                float p0 = __builtin_amdgcn_exp2f(S[kt][0] * LOG2E - m2[j]);    \
                float p1 = __builtin_amdgcn_exp2f(S[kt][1] * LOG2E - m2[j]);    \
                float p2 = __builtin_amdgcn_exp2f(S[kt][2] * LOG2E - m2[j]);    \
                float p3 = __builtin_amdgcn_exp2f(S[kt][3] * LOG2E - m2[j]);    \
                sum += (p0 + p1) + (p2 + p3);                                   \
                u32x2 w2 = {cvt_pk_bf16(p0, p1), cvt_pk_bf16(p2, p3)};          \
                *reinterpret_cast<u32x2*>(pq + kt * 8) = w2;                    \
            }                                                                   \
            l_s[j] += sum;                                                      \
        }                                                                       \
    }

    S_PHASE(0, 0)

    for (int i = 0; i < 16; ++i) {
        if (i < 15) S_PHASE(i + 1, (i + 1) & 1)

        // ---- PV(i) from own Pbuf[i&1] ----
        {
            const int n0 = (i * 4 + kg) * 64;
            const unsigned short* Phh =
                (const unsigned short*)(Pbase + (i & 1) * 18432 + wave * 1152);
            __builtin_amdgcn_s_setprio(1);
            #pragma unroll
            for (int s = 0; s < 2; ++s) {
                bf16x8 pf[2];
                #pragma unroll
                for (int j = 0; j < 2; ++j)
                    pf[j] = *reinterpret_cast<const bf16x8*>(
                        Phh + (j * 16 + low) * 72 + s * 32 + quad * 8);
                #pragma unroll
                for (int ct = 0; ct < 8; ++ct) {
                    const bf16x8 vf = *reinterpret_cast<const bf16x8*>(
                        Vb + (size_t)(ch * 128 + ct * 16 + low) * NTOK
                           + n0 + s * 32 + quad * 8);
                    #pragma unroll
                    for (int j = 0; j < 2; ++j)
                        acc[j][ct] = __builtin_amdgcn_mfma_f32_16x16x32_bf16(
                            vf, pf[j], acc[j][ct], 0, 0, 0);
                }
            }
            __builtin_amdgcn_s_setprio(0);
        }
    }
    #undef S_PHASE

    // ---- publish per-keygroup l (ch-waves have identical l; ch0 only) ----
    #pragma unroll
    for (int j = 0; j < 2; ++j) {
        l_s[j] += __shfl_xor(l_s[j], 16);
        l_s[j] += __shfl_xor(l_s[j], 32);
    }
    if (quad == 0 && ch == 0) {
        #pragma unroll
        for (int j = 0; j < 2; ++j)
            lbuf[kg * 64 + (qw * 2 + j) * 16 + low] = l_s[j];
    }
    __syncthreads();   // waves drift; all must be done with P before merge

    // ---- merge 4 kg-partials; 32 channels (16/ch-half) per round ----
    const int q = t & 63;                    // q-in-block
    const int u = t >> 6;                    // 0..15 = c15
    float invl = 0.f;
    for (int rd = 0; rd < 8; ++rd) {
        #pragma unroll
        for (int j = 0; j < 2; ++j) {
            float* sl = smem + wave * 704 + (j * 16 + low) * 22 + quad * 4;
            f32x2 lo = {acc[j][rd][0], acc[j][rd][1]};
            f32x2 hi = {acc[j][rd][2], acc[j][rd][3]};
            *reinterpret_cast<f32x2*>(sl)     = lo;
            *reinterpret_cast<f32x2*>(sl + 2) = hi;
        }
        __syncthreads();
        if (rd == 0)
            invl = 1.0f / (((lbuf[q] + lbuf[64 + q]) + (lbuf[128 + q] + lbuf[192 + q])));

        #pragma unroll
        for (int p = 0; p < 2; ++p) {
            const int half = p;
            // wave holding (qw(q), half, kg): w = (q>>5)*8 + half*4 + kg
            const int wb = (q >> 5) * 8 + half * 4;
            const int r  = (q & 31) * 22 + u;
            float O = (smem[(wb + 0) * 704 + r] + smem[(wb + 1) * 704 + r])
                    + (smem[(wb + 2) * 704 + r] + smem[(wb + 3) * 704 + r]);
            const int c = half * 128 + rd * 16 + u;
            const size_t idx = (size_t)(b * CH + c) * NTOK + q0 + q;
            out[idx] = x[idx] + O * invl;
        }
        __syncthreads();
    }
}

extern "C" void kernel_launch(void* const* d_in, const int* in_sizes, int n_in,
                              void* d_out, int out_size, void* d_ws, size_t ws_size,
                              hipStream_t stream) {
    const float* x  = (const float*)d_in[0];
    const float* Wq = (const float*)d_in[1];
    const float* bq = (const float*)d_in[2];
    const float* Wk = (const float*)d_in[3];
    const float* bk = (const float*)d_in[4];
    const float* Wv = (const float*)d_in[5];
    const float* bv = (const float*)d_in[6];
    float* out = (float*)d_out;

    unsigned short* Qh  = (unsigned short*)d_ws;                 // [B,N,32] bf16
    unsigned short* Kh  = Qh  + (size_t)BATCH * NTOK * DQK;      // [B,N,32] bf16
    unsigned short* Vh  = Kh  + (size_t)BATCH * NTOK * DQK;      // [B,C,N] bf16
    unsigned short* Wbf = Vh  + (size_t)BATCH * CH * NTOK;       // [320,256] bf16
    unsigned int*   Mk  = (unsigned int*)(Wbf + 320 * 256);      // [B] max||k||^2

    wconv<<<dim3(80), dim3(256), 0, stream>>>(Wq, Wk, Wv, Wbf, Mk);
    qkv_proj<<<dim3(512), dim3(256), 0, stream>>>(x, bq, bk, bv, Wbf,
                                                  Qh, Kh, Vh, Mk);
    attn<<<dim3(256), dim3(1024), 0, stream>>>(x, Qh, Kh, Vh, Mk, out);
}

// Round 14
// 213.918 us; speedup vs baseline: 1.5712x; 1.5712x over previous
//
#include <hip/hip_runtime.h>

#define BATCH 4
#define CH    256
#define NTOK  4096
#define DQK   32

typedef __attribute__((ext_vector_type(4))) float  f32x4;
typedef __attribute__((ext_vector_type(2))) float  f32x2;
typedef __attribute__((ext_vector_type(8))) __bf16 bf16x8;
typedef __attribute__((ext_vector_type(2))) unsigned int u32x2;
typedef __attribute__((ext_vector_type(4))) unsigned int u32x4;

// round-to-nearest-even float -> bf16 bits (cold paths)
static __device__ __forceinline__ unsigned short f2bf(float f) {
    unsigned int u = __builtin_bit_cast(unsigned int, f);
    unsigned int r = u + 0x7FFFu + ((u >> 16) & 1u);
    return (unsigned short)(r >> 16);
}
static __device__ __forceinline__ unsigned int pack2(float a, float b) {
    return (unsigned int)f2bf(a) | ((unsigned int)f2bf(b) << 16);
}
// hot-path pack: single HW instr, RTNE, a->lo b->hi
static __device__ __forceinline__ unsigned int cvt_pk_bf16(float a, float b) {
    unsigned int r;
    asm("v_cvt_pk_bf16_f32 %0, %1, %2" : "=v"(r) : "v"(a), "v"(b));
    return r;
}

// ---------------------------------------------------------------------------
// Kernel 0: convert Wq|Wk|Wv -> Wbf [320 rows][256 c] bf16; zero Mk.
// ---------------------------------------------------------------------------
__global__ __launch_bounds__(256)
void wconv(const float* __restrict__ Wq, const float* __restrict__ Wk,
           const float* __restrict__ Wv, unsigned short* __restrict__ Wbf,
           unsigned int* __restrict__ Mk)
{
    if (blockIdx.x == 0 && threadIdx.x < BATCH) Mk[threadIdx.x] = 0u;
    const int id = (blockIdx.x * 256 + threadIdx.x) * 4;
    const int r  = id >> 8;
    const int c  = id & 255;
    const float* src = (r < 32) ? (Wq + r * 256 + c)
                     : (r < 64) ? (Wk + (r - 32) * 256 + c)
                                : (Wv + (size_t)(r - 64) * 256 + c);
    float v0 = src[0], v1 = src[1], v2 = src[2], v3 = src[3];
    u32x2 p = {pack2(v0, v1), pack2(v2, v3)};
    *reinterpret_cast<u32x2*>(Wbf + id) = p;
}

// ---------------------------------------------------------------------------
// Kernel 1: QKV projection, LDS-staged coalesced x reads (R8-verified exact).
// ---------------------------------------------------------------------------
__global__ __launch_bounds__(256, 2)
void qkv_proj(const float* __restrict__ x,
              const float* __restrict__ pbq, const float* __restrict__ pbk,
              const float* __restrict__ pbv,
              const unsigned short* __restrict__ Wbf,
              unsigned short* __restrict__ Qh,
              unsigned short* __restrict__ Kh,
              unsigned short* __restrict__ Vh,
              unsigned int* __restrict__ Mk)
{
    const int t    = threadIdx.x;
    const int wave = t >> 6;
    const int lane = t & 63;
    const int low  = lane & 15;
    const int quad = lane >> 4;
    const int blk  = blockIdx.x;
    const int b    = blk >> 7;               // 128 blocks per batch
    const int tok0 = (blk & 127) * 32;

    __shared__ unsigned short xs[256 * 38];  // x^T tile bf16 [c][38]; V re-aliases

    // ---- stage x[b][:, tok0:tok0+32] -> xs (coalesced 128B segments) ----
    {
        const float* xg = x + (size_t)b * CH * NTOK + tok0;
        const int k  = t & 7;                // 4-token group
        const int c0 = t >> 3;               // 0..31
        #pragma unroll
        for (int p = 0; p < 8; ++p) {
            const int c = p * 32 + c0;
            const f32x4 v = *reinterpret_cast<const f32x4*>(
                xg + (size_t)c * NTOK + k * 4);
            unsigned int* dst = reinterpret_cast<unsigned int*>(xs + c * 38 + k * 4);
            dst[0] = cvt_pk_bf16(v[0], v[1]);
            dst[1] = cvt_pk_bf16(v[2], v[3]);
        }
    }

    // bias init: acc[j][tt], rows rtg = wave*5+j, token-tiles tt=0,1
    f32x4 acc[5][2];
    #pragma unroll
    for (int j = 0; j < 5; ++j) {
        const int rtg = wave * 5 + j;
        float bb = (rtg < 2) ? pbq[rtg * 16 + low]
                 : (rtg < 4) ? pbk[(rtg - 2) * 16 + low]
                             : pbv[(rtg - 4) * 16 + low];
        f32x4 z = {bb, bb, bb, bb};
        acc[j][0] = z; acc[j][1] = z;
    }

    __syncthreads();

    #pragma unroll
    for (int k0 = 0; k0 < 8; ++k0) {
        bf16x8 wf[5];
        #pragma unroll
        for (int j = 0; j < 5; ++j) {
            const int rtg = wave * 5 + j;
            wf[j] = *reinterpret_cast<const bf16x8*>(
                Wbf + (size_t)(rtg * 16 + low) * 256 + k0 * 32 + quad * 8);
        }
        #pragma unroll
        for (int tt = 0; tt < 2; ++tt) {
            // A fragment: token = tt*16+low, channels k0*32+quad*8+e
            const unsigned short* xsrc = xs + (k0 * 32 + quad * 8) * 38 + tt * 16 + low;
            unsigned int w0 = (unsigned int)xsrc[0 * 38] | ((unsigned int)xsrc[1 * 38] << 16);
            unsigned int w1 = (unsigned int)xsrc[2 * 38] | ((unsigned int)xsrc[3 * 38] << 16);
            unsigned int w2 = (unsigned int)xsrc[4 * 38] | ((unsigned int)xsrc[5 * 38] << 16);
            unsigned int w3 = (unsigned int)xsrc[6 * 38] | ((unsigned int)xsrc[7 * 38] << 16);
            u32x4 ap = {w0, w1, w2, w3};
            const bf16x8 af = __builtin_bit_cast(bf16x8, ap);
            #pragma unroll
            for (int j = 0; j < 5; ++j)
                acc[j][tt] = __builtin_amdgcn_mfma_f32_16x16x32_bf16(
                    af, wf[j], acc[j][tt], 0, 0, 0);
        }
    }

    // ---- Q/K epilogue ----
    #pragma unroll
    for (int j = 0; j < 5; ++j) {
        const int rtg = wave * 5 + j;
        if (rtg < 4) {
            unsigned short* dst = (rtg < 2) ? Qh : Kh;
            const int wr = (rtg & 1) * 16 + low;
            #pragma unroll
            for (int tt = 0; tt < 2; ++tt)
                #pragma unroll
                for (int reg = 0; reg < 4; ++reg) {
                    const int token = tok0 + tt * 16 + quad * 4 + reg;
                    dst[(size_t)(b * NTOK + token) * DQK + wr] = f2bf(acc[j][tt][reg]);
                }
        }
    }
    // ---- per-batch max||k||^2 (wave 0: acc[2],acc[3] = K dims 0..31) ----
    if (wave == 0) {
        #pragma unroll
        for (int tt = 0; tt < 2; ++tt) {
            f32x4 kk = acc[2][tt] * acc[2][tt] + acc[3][tt] * acc[3][tt];
            #pragma unroll
            for (int mask = 1; mask <= 8; mask <<= 1)
                #pragma unroll
                for (int reg = 0; reg < 4; ++reg)
                    kk[reg] += __shfl_xor(kk[reg], mask);
            if (low == 0) {
                #pragma unroll
                for (int reg = 0; reg < 4; ++reg)
                    atomicMax(&Mk[b], __builtin_bit_cast(unsigned int, kk[reg]));
            }
        }
    }

    // ---- V epilogue: transpose in re-aliased xs (stride 36 u16) ----
    __syncthreads();                         // all xs fragment reads done
    #pragma unroll
    for (int j = 0; j < 5; ++j) {
        const int rtg = wave * 5 + j;
        if (rtg >= 4) {
            const int c = (rtg - 4) * 16 + low;
            #pragma unroll
            for (int tt = 0; tt < 2; ++tt)
                #pragma unroll
                for (int reg = 0; reg < 4; ++reg)
                    xs[c * 36 + tt * 16 + quad * 4 + reg] = f2bf(acc[j][tt][reg]);
        }
    }
    __syncthreads();
    {
        const int k  = t & 7;
        const int c0 = t >> 3;
        #pragma unroll
        for (int p = 0; p < 8; ++p) {
            const int c = p * 32 + c0;
            const u32x2 v = *reinterpret_cast<const u32x2*>(xs + c * 36 + k * 4);
            *reinterpret_cast<u32x2*>(
                Vh + ((size_t)b * CH + c) * NTOK + tok0 + k * 4) = v;
        }
    }
}

// ---------------------------------------------------------------------------
// Kernel 2: flash attention — R8-verified kernel, byte-exact. FROZEN.
// History: the barrier-free wave-private-P loop passed in exactly this shape
// (R2/R8/R10) and failed with absmax~45 under any reorder (R3/R4/R6), a
// DS-pinning sched_barrier(0x7F) (R7), and a verified-bijective P bank
// swizzle (R13). Three theories (TBAA, DS-hoist, fence-mask) falsified —
// the corruption is code-shape-sensitive with unidentified mechanism. Only
// full sched_barrier(0) (R5, −16% perf) or this exact shape are known-good.
// Do not edit the main loop's address math, ordering, or access types.
// ---------------------------------------------------------------------------
__global__ __launch_bounds__(512, 2)
void attn(const float* __restrict__ x,
          const unsigned short* __restrict__ Qh,
          const unsigned short* __restrict__ Kh,
          const unsigned short* __restrict__ Vh,
          const unsigned int* __restrict__ Mk,
          float* __restrict__ out)
{
    const int t    = threadIdx.x;
    const int wave = t >> 6;                 // 0..7
    const int kg   = wave & 3;               // keygroup
    const int ch   = wave >> 2;              // channel half (PV only)
    const int lane = t & 63;
    const int low  = lane & 15;
    const int quad = lane >> 4;

    const int beta = blockIdx.x;             // XCD swizzle (perf heuristic)
    const int b    = (beta & 7) >> 1;
    const int q0   = (((beta >> 3) * 2) + (beta & 1)) * 64;

    // dwords: [0,36864) private P, dbuf: buf*18432 + wave*2304 + row*36;
    // [36864,37120) lbuf. Merge slabs (8 x 1408 dw) alias Pbuf0+.
    __shared__ float smem[36864 + 256];
    unsigned int* Pbase = (unsigned int*)smem;
    float* lbuf = smem + 36864;

    const float LOG2E = 1.44269504088896f;

    bf16x8 qfrag[4];
    float  m2[4];
    {
        const float M2 = __builtin_bit_cast(float, Mk[b]);
        #pragma unroll
        for (int j = 0; j < 4; ++j) {
            qfrag[j] = *reinterpret_cast<const bf16x8*>(
                Qh + (size_t)(b * NTOK + q0 + j * 16 + low) * DQK + quad * 8);
            float qn2 = 0.f;
            #pragma unroll
            for (int e = 0; e < 8; ++e) {
                float qv = (float)qfrag[j][e];
                qn2 += qv * qv;
            }
            qn2 += __shfl_xor(qn2, 16);
            qn2 += __shfl_xor(qn2, 32);
            m2[j] = __builtin_sqrtf(qn2 * M2) * (1.02f * LOG2E);
        }
    }

    f32x4 acc[4][8];
    #pragma unroll
    for (int qs = 0; qs < 4; ++qs)
        #pragma unroll
        for (int ct = 0; ct < 8; ++ct) { f32x4 z = {0.f,0.f,0.f,0.f}; acc[qs][ct] = z; }
    float l_s[4] = {0.f, 0.f, 0.f, 0.f};

    const unsigned short* Kb = Kh + (size_t)b * NTOK * DQK;
    const unsigned short* Vb = Vh + (size_t)b * CH * NTOK;

    // S for ALL 4 q-subtiles, own keygroup, into OWN P region (no sharing).
    #define S_PHASE(ii, buf)                                                    \
    {                                                                           \
        const int n0s = ((ii) * 4 + kg) * 64;                                   \
        bf16x8 kf[4];                                                           \
        _Pragma("unroll")                                                       \
        for (int kt = 0; kt < 4; ++kt)                                          \
            kf[kt] = *reinterpret_cast<const bf16x8*>(                          \
                Kb + (size_t)(n0s + kt * 16 + low) * DQK + quad * 8);           \
        _Pragma("unroll")                                                       \
        for (int j = 0; j < 4; ++j) {                                           \
            f32x4 S[4];                                                         \
            _Pragma("unroll")                                                   \
            for (int kt = 0; kt < 4; ++kt) {                                    \
                f32x4 z = {0.f,0.f,0.f,0.f};                                    \
                S[kt] = __builtin_amdgcn_mfma_f32_16x16x32_bf16(kf[kt],         \
                            qfrag[j], z, 0, 0, 0);                              \
            }                                                                   \
            float sum = 0.f;                                                    \
            unsigned int* pq = Pbase + (buf) * 18432 + wave * 2304              \
                               + (j * 16 + low) * 36 + quad * 2;                \
            _Pragma("unroll")                                                   \
            for (int kt = 0; kt < 4; ++kt) {                                    \
                float p0 = __builtin_amdgcn_exp2f(S[kt][0] * LOG2E - m2[j]);    \
                float p1 = __builtin_amdgcn_exp2f(S[kt][1] * LOG2E - m2[j]);    \
                float p2 = __builtin_amdgcn_exp2f(S[kt][2] * LOG2E - m2[j]);    \
                float p3 = __builtin_amdgcn_exp2f(S[kt][3] * LOG2E - m2[j]);    \
                sum += (p0 + p1) + (p2 + p3);                                   \
                u32x2 w2 = {cvt_pk_bf16(p0, p1), cvt_pk_bf16(p2, p3)};          \
                *reinterpret_cast<u32x2*>(pq + kt * 8) = w2;                    \
            }                                                                   \
            l_s[j] += sum;                                                      \
        }                                                                       \
    }

    S_PHASE(0, 0)

    for (int i = 0; i < 16; ++i) {
        if (i < 15) S_PHASE(i + 1, (i + 1) & 1)

        // ---- PV(i) from own Pbuf[i&1] ----
        {
            const int n0 = (i * 4 + kg) * 64;
            const unsigned short* Phh =
                (const unsigned short*)(Pbase + (i & 1) * 18432 + wave * 2304);
            __builtin_amdgcn_s_setprio(1);
            #pragma unroll
            for (int s = 0; s < 2; ++s) {
                bf16x8 pf[4];
                #pragma unroll
                for (int qs = 0; qs < 4; ++qs)
                    pf[qs] = *reinterpret_cast<const bf16x8*>(
                        Phh + (qs * 16 + low) * 72 + s * 32 + quad * 8);
                #pragma unroll
                for (int ct = 0; ct < 8; ++ct) {
                    const bf16x8 vf = *reinterpret_cast<const bf16x8*>(
                        Vb + (size_t)(ch * 128 + ct * 16 + low) * NTOK
                           + n0 + s * 32 + quad * 8);
                    #pragma unroll
                    for (int qs = 0; qs < 4; ++qs)
                        acc[qs][ct] = __builtin_amdgcn_mfma_f32_16x16x32_bf16(
                            vf, pf[qs], acc[qs][ct], 0, 0, 0);
                }
            }
            __builtin_amdgcn_s_setprio(0);
        }
    }
    #undef S_PHASE

    // ---- publish per-keygroup l (each wave computed all 4; publish own 2) ----
    #pragma unroll
    for (int j = 0; j < 4; ++j) {
        l_s[j] += __shfl_xor(l_s[j], 16);
        l_s[j] += __shfl_xor(l_s[j], 32);
    }
    if (quad == 0) {
        #pragma unroll
        for (int jj = 0; jj < 2; ++jj) {
            const int qs = 2 * ch + jj;
            lbuf[kg * 64 + qs * 16 + low] = l_s[qs];
        }
    }
    __syncthreads();   // waves may have drifted; all must be done with P

    // ---- merge 4 kg-partials, 32 channels (16 per ch-half) per round ----
    const int q = t & 63;
    const int u = t >> 6;                    // 0..7
    float invl = 0.f;
    for (int rd = 0; rd < 8; ++rd) {
        #pragma unroll
        for (int qs = 0; qs < 4; ++qs) {
            float* sl = smem + wave * 1408 + (qs * 16 + low) * 22 + quad * 4;
            f32x2 lo = {acc[qs][rd][0], acc[qs][rd][1]};
            f32x2 hi = {acc[qs][rd][2], acc[qs][rd][3]};
            *reinterpret_cast<f32x2*>(sl)     = lo;
            *reinterpret_cast<f32x2*>(sl + 2) = hi;
        }
        __syncthreads();
        if (rd == 0)
            invl = 1.0f / (((lbuf[q] + lbuf[64 + q]) + (lbuf[128 + q] + lbuf[192 + q])));

        #pragma unroll
        for (int p = 0; p < 4; ++p) {
            const int half = p >> 1;
            const int c15  = u * 2 + (p & 1);            // 0..15
            const int wb   = half * 4;
            float O = (smem[(wb + 0) * 1408 + q * 22 + c15]
                     + smem[(wb + 1) * 1408 + q * 22 + c15])
                    + (smem[(wb + 2) * 1408 + q * 22 + c15]
                     + smem[(wb + 3) * 1408 + q * 22 + c15]);
            const int c = half * 128 + rd * 16 + c15;
            const size_t idx = (size_t)(b * CH + c) * NTOK + q0 + q;
            out[idx] = x[idx] + O * invl;
        }
        __syncthreads();
    }
}

extern "C" void kernel_launch(void* const* d_in, const int* in_sizes, int n_in,
                              void* d_out, int out_size, void* d_ws, size_t ws_size,
                              hipStream_t stream) {
    const float* x  = (const float*)d_in[0];
    const float* Wq = (const float*)d_in[1];
    const float* bq = (const float*)d_in[2];
    const float* Wk = (const float*)d_in[3];
    const float* bk = (const float*)d_in[4];
    const float* Wv = (const float*)d_in[5];
    const float* bv = (const float*)d_in[6];
    float* out = (float*)d_out;

    unsigned short* Qh  = (unsigned short*)d_ws;                 // [B,N,32] bf16
    unsigned short* Kh  = Qh  + (size_t)BATCH * NTOK * DQK;      // [B,N,32] bf16
    unsigned short* Vh  = Kh  + (size_t)BATCH * NTOK * DQK;      // [B,C,N] bf16
    unsigned short* Wbf = Vh  + (size_t)BATCH * CH * NTOK;       // [320,256] bf16
    unsigned int*   Mk  = (unsigned int*)(Wbf + 320 * 256);      // [B] max||k||^2

    wconv<<<dim3(80), dim3(256), 0, stream>>>(Wq, Wk, Wv, Wbf, Mk);
    qkv_proj<<<dim3(512), dim3(256), 0, stream>>>(x, bq, bk, bv, Wbf,
                                                  Qh, Kh, Vh, Mk);
    attn<<<dim3(256), dim3(512), 0, stream>>>(x, Qh, Kh, Vh, Mk, out);
}

// Round 15
// 213.560 us; speedup vs baseline: 1.5738x; 1.0017x over previous
//
#include <hip/hip_runtime.h>

#define BATCH 4
#define CH    256
#define NTOK  4096
#define DQK   32

typedef __attribute__((ext_vector_type(4))) float  f32x4;
typedef __attribute__((ext_vector_type(2))) float  f32x2;
typedef __attribute__((ext_vector_type(8))) __bf16 bf16x8;
typedef __attribute__((ext_vector_type(2))) unsigned int u32x2;
typedef __attribute__((ext_vector_type(4))) unsigned int u32x4;

// round-to-nearest-even float -> bf16 bits (cold paths)
static __device__ __forceinline__ unsigned short f2bf(float f) {
    unsigned int u = __builtin_bit_cast(unsigned int, f);
    unsigned int r = u + 0x7FFFu + ((u >> 16) & 1u);
    return (unsigned short)(r >> 16);
}
static __device__ __forceinline__ unsigned int pack2(float a, float b) {
    return (unsigned int)f2bf(a) | ((unsigned int)f2bf(b) << 16);
}
// hot-path pack: single HW instr, RTNE, a->lo b->hi
static __device__ __forceinline__ unsigned int cvt_pk_bf16(float a, float b) {
    unsigned int r;
    asm("v_cvt_pk_bf16_f32 %0, %1, %2" : "=v"(r) : "v"(a), "v"(b));
    return r;
}

// ---------------------------------------------------------------------------
// Kernel 0: convert Wq|Wk|Wv -> Wbf [320 rows][256 c] bf16; zero Mk.
// ---------------------------------------------------------------------------
__global__ __launch_bounds__(256)
void wconv(const float* __restrict__ Wq, const float* __restrict__ Wk,
           const float* __restrict__ Wv, unsigned short* __restrict__ Wbf,
           unsigned int* __restrict__ Mk)
{
    if (blockIdx.x == 0 && threadIdx.x < BATCH) Mk[threadIdx.x] = 0u;
    const int id = (blockIdx.x * 256 + threadIdx.x) * 4;
    const int r  = id >> 8;
    const int c  = id & 255;
    const float* src = (r < 32) ? (Wq + r * 256 + c)
                     : (r < 64) ? (Wk + (r - 32) * 256 + c)
                                : (Wv + (size_t)(r - 64) * 256 + c);
    float v0 = src[0], v1 = src[1], v2 = src[2], v3 = src[3];
    u32x2 p = {pack2(v0, v1), pack2(v2, v3)};
    *reinterpret_cast<u32x2*>(Wbf + id) = p;
}

// ---------------------------------------------------------------------------
// Kernel 1: QKV projection. R15 change (isolated to this kernel; attn
// frozen): x-tile LDS layout [c][38] -> token-row-major [tok][256] with
// XOR bank swizzle  u16col ^= (tok&7)<<3  (16B granularity: preserves
// ds_read_b128 contiguity + alignment; bijective; applied on BOTH the
// staging writes and the fragment reads — rule #21).
// A-fragment gather: was 8 scalar ds_read_u16 (stride 38) + 7 or/shifts
// per fragment (128 scalar LDS reads + 64 ALU/thread total) -> now ONE
// ds_read_b128 per fragment (16/thread). Bank check: 64 lanes read 64
// distinct 16B chunks, 8 accesses/bank = structural floor (conflict-free).
// Staging pays +16 scalar u16 writes/thread (~2-way, free per m136).
// Staging global reads, Q/K/V epilogues, Mk path: byte-identical to the
// R8-verified kernel. LDS 19456 -> 18432 B (covers V-alias 9216 u16).
// ---------------------------------------------------------------------------
__global__ __launch_bounds__(256, 2)
void qkv_proj(const float* __restrict__ x,
              const float* __restrict__ pbq, const float* __restrict__ pbk,
              const float* __restrict__ pbv,
              const unsigned short* __restrict__ Wbf,
              unsigned short* __restrict__ Qh,
              unsigned short* __restrict__ Kh,
              unsigned short* __restrict__ Vh,
              unsigned int* __restrict__ Mk)
{
    const int t    = threadIdx.x;
    const int wave = t >> 6;
    const int lane = t & 63;
    const int low  = lane & 15;
    const int quad = lane >> 4;
    const int blk  = blockIdx.x;
    const int b    = blk >> 7;               // 128 blocks per batch
    const int tok0 = (blk & 127) * 32;

    // [0,8192): x^T tile bf16 [tok][256], XOR-swizzled cols.
    // V epilogue re-aliases as [c][36] (9216 u16) after a barrier.
    __shared__ unsigned short xs[256 * 36];

    // ---- stage x[b][:, tok0:tok0+32] -> xs[tok][c^] (coalesced reads) ----
    {
        const float* xg = x + (size_t)b * CH * NTOK + tok0;
        const int k  = t & 7;                // token group: tokens k*4..k*4+3
        const int c0 = t >> 3;               // 0..31
        const int tokb = k * 4;
        #pragma unroll
        for (int p = 0; p < 8; ++p) {
            const int c = p * 32 + c0;
            const f32x4 v = *reinterpret_cast<const f32x4*>(
                xg + (size_t)c * NTOK + k * 4);
            const unsigned int u0 = cvt_pk_bf16(v[0], v[1]);
            const unsigned int u1 = cvt_pk_bf16(v[2], v[3]);
            xs[(tokb + 0) * 256 + (c ^ (((tokb + 0) & 7) << 3))] = (unsigned short)u0;
            xs[(tokb + 1) * 256 + (c ^ (((tokb + 1) & 7) << 3))] = (unsigned short)(u0 >> 16);
            xs[(tokb + 2) * 256 + (c ^ (((tokb + 2) & 7) << 3))] = (unsigned short)u1;
            xs[(tokb + 3) * 256 + (c ^ (((tokb + 3) & 7) << 3))] = (unsigned short)(u1 >> 16);
        }
    }

    // bias init: acc[j][tt], rows rtg = wave*5+j, token-tiles tt=0,1
    f32x4 acc[5][2];
    #pragma unroll
    for (int j = 0; j < 5; ++j) {
        const int rtg = wave * 5 + j;
        float bb = (rtg < 2) ? pbq[rtg * 16 + low]
                 : (rtg < 4) ? pbk[(rtg - 2) * 16 + low]
                             : pbv[(rtg - 4) * 16 + low];
        f32x4 z = {bb, bb, bb, bb};
        acc[j][0] = z; acc[j][1] = z;
    }

    __syncthreads();

    #pragma unroll
    for (int k0 = 0; k0 < 8; ++k0) {
        bf16x8 wf[5];
        #pragma unroll
        for (int j = 0; j < 5; ++j) {
            const int rtg = wave * 5 + j;
            wf[j] = *reinterpret_cast<const bf16x8*>(
                Wbf + (size_t)(rtg * 16 + low) * 256 + k0 * 32 + quad * 8);
        }
        #pragma unroll
        for (int tt = 0; tt < 2; ++tt) {
            // A fragment: token row = tt*16+low; channels k0*32+quad*8..+7,
            // col XOR'd with (row&7)<<3 = (low&7)<<3 (matches write side).
            const bf16x8 af = *reinterpret_cast<const bf16x8*>(
                xs + (size_t)(tt * 16 + low) * 256
                   + ((k0 * 32 + quad * 8) ^ ((low & 7) << 3)));
            #pragma unroll
            for (int j = 0; j < 5; ++j)
                acc[j][tt] = __builtin_amdgcn_mfma_f32_16x16x32_bf16(
                    af, wf[j], acc[j][tt], 0, 0, 0);
        }
    }

    // ---- Q/K epilogue ----
    #pragma unroll
    for (int j = 0; j < 5; ++j) {
        const int rtg = wave * 5 + j;
        if (rtg < 4) {
            unsigned short* dst = (rtg < 2) ? Qh : Kh;
            const int wr = (rtg & 1) * 16 + low;
            #pragma unroll
            for (int tt = 0; tt < 2; ++tt)
                #pragma unroll
                for (int reg = 0; reg < 4; ++reg) {
                    const int token = tok0 + tt * 16 + quad * 4 + reg;
                    dst[(size_t)(b * NTOK + token) * DQK + wr] = f2bf(acc[j][tt][reg]);
                }
        }
    }
    // ---- per-batch max||k||^2 (wave 0: acc[2],acc[3] = K dims 0..31) ----
    if (wave == 0) {
        #pragma unroll
        for (int tt = 0; tt < 2; ++tt) {
            f32x4 kk = acc[2][tt] * acc[2][tt] + acc[3][tt] * acc[3][tt];
            #pragma unroll
            for (int mask = 1; mask <= 8; mask <<= 1)
                #pragma unroll
                for (int reg = 0; reg < 4; ++reg)
                    kk[reg] += __shfl_xor(kk[reg], mask);
            if (low == 0) {
                #pragma unroll
                for (int reg = 0; reg < 4; ++reg)
                    atomicMax(&Mk[b], __builtin_bit_cast(unsigned int, kk[reg]));
            }
        }
    }

    // ---- V epilogue: transpose in re-aliased xs (stride 36 u16) ----
    __syncthreads();                         // all xs fragment reads done
    #pragma unroll
    for (int j = 0; j < 5; ++j) {
        const int rtg = wave * 5 + j;
        if (rtg >= 4) {
            const int c = (rtg - 4) * 16 + low;
            #pragma unroll
            for (int tt = 0; tt < 2; ++tt)
                #pragma unroll
                for (int reg = 0; reg < 4; ++reg)
                    xs[c * 36 + tt * 16 + quad * 4 + reg] = f2bf(acc[j][tt][reg]);
        }
    }
    __syncthreads();
    {
        const int k  = t & 7;
        const int c0 = t >> 3;
        #pragma unroll
        for (int p = 0; p < 8; ++p) {
            const int c = p * 32 + c0;
            const u32x2 v = *reinterpret_cast<const u32x2*>(xs + c * 36 + k * 4);
            *reinterpret_cast<u32x2*>(
                Vh + ((size_t)b * CH + c) * NTOK + tok0 + k * 4) = v;
        }
    }
}

// ---------------------------------------------------------------------------
// Kernel 2: flash attention — R8-verified kernel, byte-exact. FROZEN.
// History: passed in exactly this shape (R2/R8/R10/R14); failed absmax~45
// under any reorder (R3/R4/R6), DS-pinning sched_barrier(0x7F) (R7), and a
// verified-bijective P swizzle (R13). Three theories falsified — corruption
// is code-shape-sensitive with unidentified mechanism. Do not edit the main
// loop's address math, ordering, or access types.
// ---------------------------------------------------------------------------
__global__ __launch_bounds__(512, 2)
void attn(const float* __restrict__ x,
          const unsigned short* __restrict__ Qh,
          const unsigned short* __restrict__ Kh,
          const unsigned short* __restrict__ Vh,
          const unsigned int* __restrict__ Mk,
          float* __restrict__ out)
{
    const int t    = threadIdx.x;
    const int wave = t >> 6;                 // 0..7
    const int kg   = wave & 3;               // keygroup
    const int ch   = wave >> 2;              // channel half (PV only)
    const int lane = t & 63;
    const int low  = lane & 15;
    const int quad = lane >> 4;

    const int beta = blockIdx.x;             // XCD swizzle (perf heuristic)
    const int b    = (beta & 7) >> 1;
    const int q0   = (((beta >> 3) * 2) + (beta & 1)) * 64;

    // dwords: [0,36864) private P, dbuf: buf*18432 + wave*2304 + row*36;
    // [36864,37120) lbuf. Merge slabs (8 x 1408 dw) alias Pbuf0+.
    __shared__ float smem[36864 + 256];
    unsigned int* Pbase = (unsigned int*)smem;
    float* lbuf = smem + 36864;

    const float LOG2E = 1.44269504088896f;

    bf16x8 qfrag[4];
    float  m2[4];
    {
        const float M2 = __builtin_bit_cast(float, Mk[b]);
        #pragma unroll
        for (int j = 0; j < 4; ++j) {
            qfrag[j] = *reinterpret_cast<const bf16x8*>(
                Qh + (size_t)(b * NTOK + q0 + j * 16 + low) * DQK + quad * 8);
            float qn2 = 0.f;
            #pragma unroll
            for (int e = 0; e < 8; ++e) {
                float qv = (float)qfrag[j][e];
                qn2 += qv * qv;
            }
            qn2 += __shfl_xor(qn2, 16);
            qn2 += __shfl_xor(qn2, 32);
            m2[j] = __builtin_sqrtf(qn2 * M2) * (1.02f * LOG2E);
        }
    }

    f32x4 acc[4][8];
    #pragma unroll
    for (int qs = 0; qs < 4; ++qs)
        #pragma unroll
        for (int ct = 0; ct < 8; ++ct) { f32x4 z = {0.f,0.f,0.f,0.f}; acc[qs][ct] = z; }
    float l_s[4] = {0.f, 0.f, 0.f, 0.f};

    const unsigned short* Kb = Kh + (size_t)b * NTOK * DQK;
    const unsigned short* Vb = Vh + (size_t)b * CH * NTOK;

    // S for ALL 4 q-subtiles, own keygroup, into OWN P region (no sharing).
    #define S_PHASE(ii, buf)                                                    \
    {                                                                           \
        const int n0s = ((ii) * 4 + kg) * 64;                                   \
        bf16x8 kf[4];                                                           \
        _Pragma("unroll")                                                       \
        for (int kt = 0; kt < 4; ++kt)                                          \
            kf[kt] = *reinterpret_cast<const bf16x8*>(                          \
                Kb + (size_t)(n0s + kt * 16 + low) * DQK + quad * 8);           \
        _Pragma("unroll")                                                       \
        for (int j = 0; j < 4; ++j) {                                           \
            f32x4 S[4];                                                         \
            _Pragma("unroll")                                                   \
            for (int kt = 0; kt < 4; ++kt) {                                    \
                f32x4 z = {0.f,0.f,0.f,0.f};                                    \
                S[kt] = __builtin_amdgcn_mfma_f32_16x16x32_bf16(kf[kt],         \
                            qfrag[j], z, 0, 0, 0);                              \
            }                                                                   \
            float sum = 0.f;                                                    \
            unsigned int* pq = Pbase + (buf) * 18432 + wave * 2304              \
                               + (j * 16 + low) * 36 + quad * 2;                \
            _Pragma("unroll")                                                   \
            for (int kt = 0; kt < 4; ++kt) {                                    \
                float p0 = __builtin_amdgcn_exp2f(S[kt][0] * LOG2E - m2[j]);    \
                float p1 = __builtin_amdgcn_exp2f(S[kt][1] * LOG2E - m2[j]);    \
                float p2 = __builtin_amdgcn_exp2f(S[kt][2] * LOG2E - m2[j]);    \
                float p3 = __builtin_amdgcn_exp2f(S[kt][3] * LOG2E - m2[j]);    \
                sum += (p0 + p1) + (p2 + p3);                                   \
                u32x2 w2 = {cvt_pk_bf16(p0, p1), cvt_pk_bf16(p2, p3)};          \
                *reinterpret_cast<u32x2*>(pq + kt * 8) = w2;                    \
            }                                                                   \
            l_s[j] += sum;                                                      \
        }                                                                       \
    }

    S_PHASE(0, 0)

    for (int i = 0; i < 16; ++i) {
        if (i < 15) S_PHASE(i + 1, (i + 1) & 1)

        // ---- PV(i) from own Pbuf[i&1] ----
        {
            const int n0 = (i * 4 + kg) * 64;
            const unsigned short* Phh =
                (const unsigned short*)(Pbase + (i & 1) * 18432 + wave * 2304);
            __builtin_amdgcn_s_setprio(1);
            #pragma unroll
            for (int s = 0; s < 2; ++s) {
                bf16x8 pf[4];
                #pragma unroll
                for (int qs = 0; qs < 4; ++qs)
                    pf[qs] = *reinterpret_cast<const bf16x8*>(
                        Phh + (qs * 16 + low) * 72 + s * 32 + quad * 8);
                #pragma unroll
                for (int ct = 0; ct < 8; ++ct) {
                    const bf16x8 vf = *reinterpret_cast<const bf16x8*>(
                        Vb + (size_t)(ch * 128 + ct * 16 + low) * NTOK
                           + n0 + s * 32 + quad * 8);
                    #pragma unroll
                    for (int qs = 0; qs < 4; ++qs)
                        acc[qs][ct] = __builtin_amdgcn_mfma_f32_16x16x32_bf16(
                            vf, pf[qs], acc[qs][ct], 0, 0, 0);
                }
            }
            __builtin_amdgcn_s_setprio(0);
        }
    }
    #undef S_PHASE

    // ---- publish per-keygroup l (each wave computed all 4; publish own 2) ----
    #pragma unroll
    for (int j = 0; j < 4; ++j) {
        l_s[j] += __shfl_xor(l_s[j], 16);
        l_s[j] += __shfl_xor(l_s[j], 32);
    }
    if (quad == 0) {
        #pragma unroll
        for (int jj = 0; jj < 2; ++jj) {
            const int qs = 2 * ch + jj;
            lbuf[kg * 64 + qs * 16 + low] = l_s[qs];
        }
    }
    __syncthreads();   // waves may have drifted; all must be done with P

    // ---- merge 4 kg-partials, 32 channels (16 per ch-half) per round ----
    const int q = t & 63;
    const int u = t >> 6;                    // 0..7
    float invl = 0.f;
    for (int rd = 0; rd < 8; ++rd) {
        #pragma unroll
        for (int qs = 0; qs < 4; ++qs) {
            float* sl = smem + wave * 1408 + (qs * 16 + low) * 22 + quad * 4;
            f32x2 lo = {acc[qs][rd][0], acc[qs][rd][1]};
            f32x2 hi = {acc[qs][rd][2], acc[qs][rd][3]};
            *reinterpret_cast<f32x2*>(sl)     = lo;
            *reinterpret_cast<f32x2*>(sl + 2) = hi;
        }
        __syncthreads();
        if (rd == 0)
            invl = 1.0f / (((lbuf[q] + lbuf[64 + q]) + (lbuf[128 + q] + lbuf[192 + q])));

        #pragma unroll
        for (int p = 0; p < 4; ++p) {
            const int half = p >> 1;
            const int c15  = u * 2 + (p & 1);            // 0..15
            const int wb   = half * 4;
            float O = (smem[(wb + 0) * 1408 + q * 22 + c15]
                     + smem[(wb + 1) * 1408 + q * 22 + c15])
                    + (smem[(wb + 2) * 1408 + q * 22 + c15]
                     + smem[(wb + 3) * 1408 + q * 22 + c15]);
            const int c = half * 128 + rd * 16 + c15;
            const size_t idx = (size_t)(b * CH + c) * NTOK + q0 + q;
            out[idx] = x[idx] + O * invl;
        }
        __syncthreads();
    }
}

extern "C" void kernel_launch(void* const* d_in, const int* in_sizes, int n_in,
                              void* d_out, int out_size, void* d_ws, size_t ws_size,
                              hipStream_t stream) {
    const float* x  = (const float*)d_in[0];
    const float* Wq = (const float*)d_in[1];
    const float* bq = (const float*)d_in[2];
    const float* Wk = (const float*)d_in[3];
    const float* bk = (const float*)d_in[4];
    const float* Wv = (const float*)d_in[5];
    const float* bv = (const float*)d_in[6];
    float* out = (float*)d_out;

    unsigned short* Qh  = (unsigned short*)d_ws;                 // [B,N,32] bf16
    unsigned short* Kh  = Qh  + (size_t)BATCH * NTOK * DQK;      // [B,N,32] bf16
    unsigned short* Vh  = Kh  + (size_t)BATCH * NTOK * DQK;      // [B,C,N] bf16
    unsigned short* Wbf = Vh  + (size_t)BATCH * CH * NTOK;       // [320,256] bf16
    unsigned int*   Mk  = (unsigned int*)(Wbf + 320 * 256);      // [B] max||k||^2

    wconv<<<dim3(80), dim3(256), 0, stream>>>(Wq, Wk, Wv, Wbf, Mk);
    qkv_proj<<<dim3(512), dim3(256), 0, stream>>>(x, bq, bk, bv, Wbf,
                                                  Qh, Kh, Vh, Mk);
    attn<<<dim3(256), dim3(512), 0, stream>>>(x, Qh, Kh, Vh, Mk, out);
}